// Round 10
// baseline (6864.619 us; speedup 1.0000x reference)
//
#include <hip/hip_runtime.h>
#include <hip/hip_bf16.h>
#include <stdint.h>

#define T_STEPS 512
#define NBATCH 64
#define HID 1024
#define NGATE 4096
#define NLAYERS 2
#define BH (NBATCH * HID)            // 65536
#define TBH (T_STEPS * NBATCH * HID) // 33554432
#define WEL ((size_t)NLAYERS * NGATE * HID)
#define NBLK 256

typedef __attribute__((ext_vector_type(8))) short short8;
typedef __attribute__((ext_vector_type(4))) float f32x4;

__device__ __forceinline__ ushort f2bf(float f) {
  union { float f; uint32_t i; } u; u.f = f;
  return (ushort)((u.i + 0x7fffu + ((u.i >> 16) & 1u)) >> 16);  // RNE
}

// ---- A-load pipe: 16 rotating slots, counted vmcnt, 32 loads per wave-step.
// ISSC = cached load (x, h0 ring: addresses never rewritten within dispatch).
// ISSU = sc0 sc1 cross-XCD-coherent (h1 double buffer, addresses reused).
// VMW ties the slot reg through the wait ("+v") -> MFMA data-depends on the WAIT.
#define ISSC(S, M, OFF) \
  asm volatile("global_load_dwordx4 %0, %1, off offset:" #OFF \
               : "=v"(fr[S]) : "v"(aP[M]));
#define ISSU(S, M, OFF) \
  asm volatile("global_load_dwordx4 %0, %1, off offset:" #OFF " sc0 sc1" \
               : "=v"(fr[S]) : "v"(aP[M]));
#define VMW(N, SLOT) \
  asm volatile("s_waitcnt vmcnt(" #N ")" : "+v"(fr[SLOT]));
#define CON(S, M, KC) { \
    accA[M] = __builtin_amdgcn_mfma_f32_16x16x32_bf16(fr[S], breg[0][KC], accA[M], 0, 0, 0); \
    accB[M] = __builtin_amdgcn_mfma_f32_16x16x32_bf16(fr[S], breg[1][KC], accB[M], 0, 0, 0); }

// issue order = consume order: slot = kc*4+m (m fastest). B-frags are registers.
#define PIPE(I) \
  I(0,0,0)    I(1,1,0)    I(2,2,0)    I(3,3,0)   \
  I(4,0,64)   I(5,1,64)   I(6,2,64)   I(7,3,64)  \
  I(8,0,128)  I(9,1,128)  I(10,2,128) I(11,3,128)\
  I(12,0,192) I(13,1,192) I(14,2,192) I(15,3,192)\
  VMW(15,0)  CON(0,0,0)  I(0,0,256)  \
  VMW(15,1)  CON(1,1,0)  I(1,1,256)  \
  VMW(15,2)  CON(2,2,0)  I(2,2,256)  \
  VMW(15,3)  CON(3,3,0)  I(3,3,256)  \
  VMW(15,4)  CON(4,0,1)  I(4,0,320)  \
  VMW(15,5)  CON(5,1,1)  I(5,1,320)  \
  VMW(15,6)  CON(6,2,1)  I(6,2,320)  \
  VMW(15,7)  CON(7,3,1)  I(7,3,320)  \
  VMW(15,8)  CON(8,0,2)  I(8,0,384)  \
  VMW(15,9)  CON(9,1,2)  I(9,1,384)  \
  VMW(15,10) CON(10,2,2) I(10,2,384) \
  VMW(15,11) CON(11,3,2) I(11,3,384) \
  VMW(15,12) CON(12,0,3) I(12,0,448) \
  VMW(15,13) CON(13,1,3) I(13,1,448) \
  VMW(15,14) CON(14,2,3) I(14,2,448) \
  VMW(15,15) CON(15,3,3) I(15,3,448) \
  VMW(15,0)  CON(0,0,4)  \
  VMW(14,1)  CON(1,1,4)  \
  VMW(13,2)  CON(2,2,4)  \
  VMW(12,3)  CON(3,3,4)  \
  VMW(11,4)  CON(4,0,5)  \
  VMW(10,5)  CON(5,1,5)  \
  VMW(9,6)   CON(6,2,5)  \
  VMW(8,7)   CON(7,3,5)  \
  VMW(7,8)   CON(8,0,6)  \
  VMW(6,9)   CON(9,1,6)  \
  VMW(5,10)  CON(10,2,6) \
  VMW(4,11)  CON(11,3,6) \
  VMW(3,12)  CON(12,0,7) \
  VMW(2,13)  CON(13,1,7) \
  VMW(1,14)  CON(14,2,7) \
  VMW(0,15)  CON(15,3,7)

// ---------------- elementwise helpers ----------------
__global__ void k_f32_to_bf16(const float* __restrict__ in, ushort* __restrict__ out, int n) {
  int i = (blockIdx.x * blockDim.x + threadIdx.x) * 4;
  if (i >= n) return;
  const float4 v = *reinterpret_cast<const float4*>(in + i);
  ushort4 o; o.x = f2bf(v.x); o.y = f2bf(v.y); o.z = f2bf(v.z); o.w = f2bf(v.w);
  *reinterpret_cast<ushort4*>(out + i) = o;
}
__global__ void k_zero(int* p, int n) {
  int i = blockIdx.x * blockDim.x + threadIdx.x;
  if (i < n) p[i] = 0;
}

// ---------------- persistent fused scan ----------------
struct ScanP {
  const ushort* wih; const ushort* whh;
  const ushort* xb;  const ushort* hinit;
  ushort* h0r;                            // layer-0 h ring (T_STEPS slots)
  ushort* h1d;                            // layer-1 h double buffer
  const float* c0; const float* bi; const float* bh;
  float* out; int* bar;
};

// Root+release barrier (monotonic, relaxed-only, no resets). Proven r8/r9.
__device__ __forceinline__ void gbar(int* bar, int phase, int stripe, bool isRoot) {
  __syncthreads();
  if (threadIdx.x == 0) {
    __hip_atomic_fetch_add(bar + stripe * 16, 1, __ATOMIC_RELAXED, __HIP_MEMORY_SCOPE_AGENT);
    if (isRoot) {
      const int target = (phase + 1) * NBLK;
      for (;;) {
        int sum = 0;
#pragma unroll
        for (int i = 0; i < 16; ++i)
          sum += __hip_atomic_load(bar + i * 16, __ATOMIC_RELAXED, __HIP_MEMORY_SCOPE_AGENT);
        if (sum >= target) break;
        __builtin_amdgcn_s_sleep(1);
      }
      __hip_atomic_store(bar + 256, phase + 1, __ATOMIC_RELAXED, __HIP_MEMORY_SCOPE_AGENT);
    } else {
      while (__hip_atomic_load(bar + 256, __ATOMIC_RELAXED, __HIP_MEMORY_SCOPE_AGENT) < phase + 1)
        __builtin_amdgcn_s_sleep(2);
    }
  }
  __syncthreads();
  __builtin_amdgcn_sched_barrier(0);
}

// 256 blocks x 512 threads (8 waves). Blocks 0..127 = layer0 step s; 128..255 =
// layer1 step s-1. Wave w: K-slice (w&3)*256 of source (w<4 ? lowK : highK).
// B fragments (W slice) live in REGISTERS for the whole kernel (64 VGPR/lane);
// LDS carries only the 8 per-wave partial C tiles (full overwrite each phase).
__global__ __launch_bounds__(512, 1) void k_scan(ScanP p) {
  __shared__ float glds[8][32][68];   // [wave][gate-col][row(batch), padded] ~68 KB
  const int tid = threadIdx.x, wave = tid >> 6, lane = tid & 63;
  const bool isL1 = blockIdx.x >= 128;
  const int cb = isL1 ? (int)blockIdx.x - 128 : (int)blockIdx.x;
  const int j0 = cb * 8;
  const int stripe = blockIdx.x & 15;
  const bool isRoot = (blockIdx.x == 0);
  const bool hiSrc = wave >= 4;
  const int koff = (wave & 3) * 256;

  // ---- B preload into registers (W static across all steps) ----
  const ushort* wihL = p.wih + (isL1 ? (size_t)NGATE * HID : 0);
  const ushort* whhL = p.whh + (isL1 ? (size_t)NGATE * HID : 0);
  const ushort* bsrc = hiSrc ? whhL : wihL;
  short8 breg[2][8];
#pragma unroll
  for (int t = 0; t < 2; ++t) {
    const int i = t * 16 + (lane & 15);
    const int g = (i >> 3) * 1024 + j0 + (i & 7);
    const ushort* bp = bsrc + (size_t)g * 1024 + koff + (lane >> 4) * 8;
#pragma unroll
    for (int kc = 0; kc < 8; ++kc) breg[t][kc] = *(const short8*)(bp + kc * 32);
  }

  // ---- epilogue geometry: thread -> (b = tid>>3, jl = tid&7) ----
  const int eb = tid >> 3, jl = tid & 7, jj = j0 + jl;
  const int lofs = isL1 ? NGATE : 0;
  float creg = p.c0[(isL1 ? BH : 0) + eb * 1024 + jj];
  float bias[4];
#pragma unroll
  for (int g = 0; g < 4; ++g)
    bias[g] = p.bi[lofs + g * 1024 + jj] + p.bh[lofs + g * 1024 + jj];

  const size_t arow = (size_t)(lane & 15) * 1024 + koff + (lane >> 4) * 8;

  for (int s = 0; s < T_STEPS + 1; ++s) {
    const bool act = isL1 ? (s >= 1) : (s < T_STEPS);
    if (act) {
      const ushort* src;
      if (!isL1) src = hiSrc ? ((s == 0) ? p.hinit : p.h0r + (size_t)(s - 1) * BH)
                             : (p.xb + (size_t)s * BH);
      else       src = hiSrc ? ((s == 1) ? p.hinit + BH : p.h1d + (size_t)(s & 1) * BH)
                             : (p.h0r + (size_t)(s - 1) * BH);
      const ushort* base = src + arow;
      const ushort* aP[4] = { base, base + 16 * 1024, base + 32 * 1024, base + 48 * 1024 };
      f32x4 accA[4], accB[4];
#pragma unroll
      for (int m = 0; m < 4; ++m) {
        accA[m] = (f32x4){0.f, 0.f, 0.f, 0.f};
        accB[m] = (f32x4){0.f, 0.f, 0.f, 0.f};
      }
      short8 fr[16];
      if (isL1 && hiSrc) { PIPE(ISSU) } else { PIPE(ISSC) }

      // partial C tiles -> LDS (full overwrite; col = lane&15 (+16), rows 4-contig)
      {
        const int r0 = lane & 15, q4 = (lane >> 4) * 4;
#pragma unroll
        for (int m = 0; m < 4; ++m) {
          *(f32x4*)&glds[wave][r0][m * 16 + q4]      = accA[m];
          *(f32x4*)&glds[wave][16 + r0][m * 16 + q4] = accB[m];
        }
      }
      __syncthreads();

      // epilogue: sum 8 partials (fixed order, deterministic) + bias
      float v[4];
#pragma unroll
      for (int g = 0; g < 4; ++g) {
        float t = bias[g];
#pragma unroll
        for (int w = 0; w < 8; ++w) t += glds[w][g * 8 + jl][eb];
        v[g] = t;
      }
      float c = creg;
      const float si = 1.f / (1.f + __expf(-v[0]));
      const float sf = 1.f / (1.f + __expf(-v[1]));
      const float tg = tanhf(v[2]);
      const float so = 1.f / (1.f + __expf(-v[3]));
      c = sf * c + si * tg;
      const float h = so * tanhf(c);
      creg = c;

      // h store: pack 2 bf16 per dword across thread pairs (proven r5 path)
      const uint32_t hu = (uint32_t)f2bf(h);
      const uint32_t other = __shfl_xor(hu, 1);
      ushort* hdst = (!isL1) ? (p.h0r + (size_t)s * BH)
                             : (p.h1d + (size_t)((s - 1) & 1) * BH);
      if (!(tid & 1)) {
        uint32_t* hw = (uint32_t*)(hdst + eb * 1024 + jj);
        const uint32_t packed = hu | (other << 16);
        __hip_atomic_store(hw, packed, __ATOMIC_RELAXED, __HIP_MEMORY_SCOPE_AGENT);
        uint32_t chk = __hip_atomic_load(hw, __ATOMIC_RELAXED, __HIP_MEMORY_SCOPE_AGENT);
        asm volatile("" :: "v"(chk));
      }

      if (isL1) {
        p.out[(size_t)(s - 1) * BH + eb * 1024 + jj] = h;
        if (s - 1 == T_STEPS - 1) {
          p.out[(size_t)TBH + BH + eb * 1024 + jj] = h;
          p.out[(size_t)TBH + 3 * BH + eb * 1024 + jj] = c;
        }
      } else if (s == T_STEPS - 1) {
        p.out[(size_t)TBH + eb * 1024 + jj] = h;
        p.out[(size_t)TBH + 2 * BH + eb * 1024 + jj] = c;
      }
    }
    gbar(p.bar, s, stripe, isRoot);
  }
}

// ---------------- host ----------------
extern "C" void kernel_launch(void* const* d_in, const int* in_sizes, int n_in,
                              void* d_out, int out_size, void* d_ws, size_t ws_size,
                              hipStream_t stream) {
  const float* x    = (const float*)d_in[0];
  const float* h0   = (const float*)d_in[1];
  const float* c0   = (const float*)d_in[2];
  const float* w_ih = (const float*)d_in[3];
  const float* w_hh = (const float*)d_in[4];
  const float* b_ih = (const float*)d_in[5];
  const float* b_hh = (const float*)d_in[6];
  float* out = (float*)d_out;

  ushort* xb    = (ushort*)d_ws;
  ushort* wihb  = xb + (size_t)TBH;
  ushort* whhb  = wihb + WEL;
  ushort* hinit = whhb + WEL;
  ushort* h0r   = hinit + 2 * (size_t)BH;            // ring: T_STEPS slots
  ushort* h1d   = h0r + (size_t)TBH;
  int*    bar   = (int*)(h1d + 2 * (size_t)BH);

  const size_t need = ((size_t)2 * TBH + 2 * WEL + 4 * (size_t)BH) * 2 + 4096;
  if (ws_size < need) return;  // loud failure: d_out stays poisoned

  { int n = TBH;        k_f32_to_bf16<<<(n / 4 + 255) / 256, 256, 0, stream>>>(x, xb, n); }
  { int n = (int)WEL;   k_f32_to_bf16<<<(n / 4 + 255) / 256, 256, 0, stream>>>(w_ih, wihb, n); }
  { int n = (int)WEL;   k_f32_to_bf16<<<(n / 4 + 255) / 256, 256, 0, stream>>>(w_hh, whhb, n); }
  { int n = 2 * BH;     k_f32_to_bf16<<<(n / 4 + 255) / 256, 256, 0, stream>>>(h0, hinit, n); }
  k_zero<<<2, 256, 0, stream>>>(bar, 512);

  ScanP sp;
  sp.wih = wihb; sp.whh = whhb;
  sp.xb = xb; sp.hinit = hinit;
  sp.h0r = h0r; sp.h1d = h1d;
  sp.c0 = c0; sp.bi = b_ih; sp.bh = b_hh;
  sp.out = out; sp.bar = bar;

  void* kp[1] = {&sp};
  hipLaunchCooperativeKernel(reinterpret_cast<void*>(&k_scan),
                             dim3(NBLK), dim3(512), kp, 0, stream);
}